// Round 2
// baseline (142.006 us; speedup 1.0000x reference)
//
#include <hip/hip_runtime.h>

// EvoAttn: causal self-attention with Q=K=V = x.reshape(B,L,H,D).
// B=2 H=16 L=2048 D=128, fp32 in/out, bf16 MFMA compute.

#define TL 2048
#define TE 2048
#define TD 128
#define QB 64
#define KB 64

typedef __attribute__((ext_vector_type(8))) short bf16x8;
typedef __attribute__((ext_vector_type(4))) float f32x4;
typedef __attribute__((ext_vector_type(8))) unsigned short u16x8;
typedef __attribute__((ext_vector_type(4))) unsigned short u16x4;

// (1/sqrt(128)) * log2(e)
#define SCALE_LOG2E 0.12751879f

__device__ __forceinline__ unsigned short f2bf(float f) {
  unsigned int u = __builtin_bit_cast(unsigned int, f);
  u += 0x7fffu + ((u >> 16) & 1u);   // RNE
  return (unsigned short)(u >> 16);
}

__device__ __forceinline__ f32x4 mfma16(bf16x8 a, bf16x8 b, f32x4 c) {
  return __builtin_amdgcn_mfma_f32_16x16x32_bf16(a, b, c, 0, 0, 0);
}

// kv: [64 rows k][128 d] bf16, row stride 256B, byte ^= (k&7)<<4
// kvt:[128 rows d][64 k] bf16, row stride 128B, byte ^= (d&7)<<4
__device__ __forceinline__ void stage_tile(const float* __restrict__ src,
                                           unsigned short* kv, unsigned short* kvt,
                                           int t) {
  const int kr = (t >> 4) << 2;   // 4 consecutive k-rows per thread
  const int d0 = (t & 15) << 3;   // 8 d-cols per thread
  unsigned short c[4][8];
#pragma unroll
  for (int rr = 0; rr < 4; ++rr) {
    const float* p = src + (kr + rr) * TE + d0;
    const float4 a = *(const float4*)p;
    const float4 b = *(const float4*)(p + 4);
    c[rr][0] = f2bf(a.x); c[rr][1] = f2bf(a.y); c[rr][2] = f2bf(a.z); c[rr][3] = f2bf(a.w);
    c[rr][4] = f2bf(b.x); c[rr][5] = f2bf(b.y); c[rr][6] = f2bf(b.z); c[rr][7] = f2bf(b.w);
  }
#pragma unroll
  for (int rr = 0; rr < 4; ++rr) {
    const int r = kr + rr;
    u16x8 o = {c[rr][0], c[rr][1], c[rr][2], c[rr][3],
               c[rr][4], c[rr][5], c[rr][6], c[rr][7]};
    const int off = (r * 256 + d0 * 2) ^ ((r & 7) << 4);
    *(u16x8*)((char*)kv + off) = o;
  }
#pragma unroll
  for (int cc = 0; cc < 8; ++cc) {
    const int d = d0 + cc;
    u16x4 o = {c[0][cc], c[1][cc], c[2][cc], c[3][cc]};
    const int off = (d * 128 + kr * 2) ^ ((d & 7) << 4);
    *(u16x4*)((char*)kvt + off) = o;
  }
}

__device__ __forceinline__ bf16x8 ld256(const unsigned short* base, int row, int inrow) {
  const int off = (row * 256 + inrow) ^ ((row & 7) << 4);
  return *(const bf16x8*)((const char*)base + off);
}
__device__ __forceinline__ bf16x8 ld128(const unsigned short* base, int row, int inrow) {
  const int off = (row * 128 + inrow) ^ ((row & 7) << 4);
  return *(const bf16x8*)((const char*)base + off);
}

__global__ void __launch_bounds__(256)
evo_attn(const float* __restrict__ x, float* __restrict__ out) {
  __shared__ unsigned short kv[QB * TD];    // 16 KB
  __shared__ unsigned short kvt[TD * KB];   // 16 KB
  __shared__ unsigned short pl[4 * 16 * KB];// 8 KB (per-wave P tiles)

  const int t = threadIdx.x;
  const int lane = t & 63;
  const int w = t >> 6;        // wave 0..3, owns q rows [16w,16w+16)
  const int g = lane >> 4;     // lane group 0..3
  const int q15 = lane & 15;

  const int bh = blockIdx.x & 31;
  const int qt = 31 - (blockIdx.x >> 5);   // heavy (large qt) blocks first
  const int b = bh >> 4;
  const int h = bh & 15;
  const float* xb = x + b * (TL * TE) + h * TD;
  const int q0 = qt * QB;

  // Stage the Q tile: it is also the diagonal KV tile.
  stage_tile(xb + q0 * TE, kv, kvt, t);
  __syncthreads();

  // Q fragments: lane holds Q[q0+16w+q15][c*32 + g*8 + i]
  bf16x8 qf[4];
#pragma unroll
  for (int c = 0; c < 4; ++c)
    qf[c] = ld256(kv, 16 * w + q15, c * 64 + g * 16);

  f32x4 acc[8];
#pragma unroll
  for (int dt = 0; dt < 8; ++dt) acc[dt] = (f32x4){0.f, 0.f, 0.f, 0.f};
  float mrun = -1e30f;
  float lrun = 0.f;

  unsigned short* plw = pl + w * (16 * KB);

  // s = 0: diagonal tile (masked, reuses initial staging). s>0: tile k0=(s-1)*64.
  for (int s = 0; s <= qt; ++s) {
    if (s > 0) {
      __syncthreads();                       // all waves done with previous tile
      stage_tile(xb + (s - 1) * KB * TE, kv, kvt, t);
      __syncthreads();
    }

    // S^T = K * Q^T : D[row=k_local][col=q_local]; lane: q = q15 (fixed!),
    // k = kt*16 + g*4 + r
    float sv[16];
#pragma unroll
    for (int kt = 0; kt < 4; ++kt) {
      f32x4 st = (f32x4){0.f, 0.f, 0.f, 0.f};
#pragma unroll
      for (int c = 0; c < 4; ++c) {
        bf16x8 kf = ld256(kv, kt * 16 + q15, c * 64 + g * 16);
        st = mfma16(kf, qf[c], st);
      }
#pragma unroll
      for (int r = 0; r < 4; ++r) sv[kt * 4 + r] = st[r] * SCALE_LOG2E;
    }

    if (s == 0) {  // causal mask within the diagonal 64x64 block
      const int qrel = 16 * w + q15;
#pragma unroll
      for (int kt = 0; kt < 4; ++kt)
#pragma unroll
        for (int r = 0; r < 4; ++r)
          if (kt * 16 + g * 4 + r > qrel) sv[kt * 4 + r] = -1e30f;
    }

    // online softmax (exp2 domain); all 16 in-lane values share one q-row.
    // Reduce max across the 4 g-groups (lanes differing in bits 4,5).
    float tmax = sv[0];
#pragma unroll
    for (int i = 1; i < 16; ++i) tmax = fmaxf(tmax, sv[i]);
    tmax = fmaxf(tmax, __shfl_xor(tmax, 16));
    tmax = fmaxf(tmax, __shfl_xor(tmax, 32));

    const float mnew = fmaxf(mrun, tmax);
    const float al = exp2f(mrun - mnew);   // g-uniform (mrun,mnew g-uniform)
    mrun = mnew;

    float psum = 0.f;
    unsigned short pb[16];
#pragma unroll
    for (int i = 0; i < 16; ++i) {
      const float p = exp2f(sv[i] - mnew);
      psum += p;
      pb[i] = f2bf(p);
    }
    lrun = lrun * al + psum;   // per-lane PARTIAL sum (reduced across g at end)

    // P^T -> LDS as P[q][k] (bf16) for the PV A-fragments
#pragma unroll
    for (int kt = 0; kt < 4; ++kt) {
      u16x4 o = {pb[kt * 4], pb[kt * 4 + 1], pb[kt * 4 + 2], pb[kt * 4 + 3]};
      const int off = (q15 * 128 + kt * 32 + g * 8) ^ ((q15 & 7) << 4);
      *(u16x4*)((char*)plw + off) = o;
    }
    asm volatile("s_waitcnt lgkmcnt(0)" ::: "memory");

    // O rescale: acc rows are q_local = g*4+r, alpha lives at lane q15==that
    float ar[4];
#pragma unroll
    for (int r = 0; r < 4; ++r) ar[r] = __shfl(al, g * 4 + r);
#pragma unroll
    for (int dt = 0; dt < 8; ++dt)
#pragma unroll
      for (int r = 0; r < 4; ++r) acc[dt][r] *= ar[r];

    // PV: acc[dt] += P(16xKB) * V(KBx16 slice dt)
    bf16x8 pa0 = ld128(plw, q15, g * 16);
    bf16x8 pa1 = ld128(plw, q15, 64 + g * 16);
#pragma unroll
    for (int dt = 0; dt < 8; ++dt) {
      bf16x8 vb0 = ld128(kvt, dt * 16 + q15, g * 16);
      bf16x8 vb1 = ld128(kvt, dt * 16 + q15, 64 + g * 16);
      acc[dt] = mfma16(pa0, vb0, acc[dt]);
      acc[dt] = mfma16(pa1, vb1, acc[dt]);
    }
  }

  // Full row sum: combine the 4 g-groups' partial sums.
  lrun += __shfl_xor(lrun, 16);
  lrun += __shfl_xor(lrun, 32);

  const float inv = 1.f / lrun;
  float ir[4];
#pragma unroll
  for (int r = 0; r < 4; ++r) ir[r] = __shfl(inv, g * 4 + r);

  float* ob = out + (b * TL + q0 + 16 * w) * TE + h * TD;
#pragma unroll
  for (int dt = 0; dt < 8; ++dt)
#pragma unroll
    for (int r = 0; r < 4; ++r)
      ob[(g * 4 + r) * TE + dt * 16 + q15] = acc[dt][r] * ir[r];
}

extern "C" void kernel_launch(void* const* d_in, const int* in_sizes, int n_in,
                              void* d_out, int out_size, void* d_ws, size_t ws_size,
                              hipStream_t stream) {
  const float* x = (const float*)d_in[0];
  float* out = (float*)d_out;
  (void)in_sizes; (void)n_in; (void)out_size; (void)d_ws; (void)ws_size;
  evo_attn<<<dim3(32 * 32), dim3(256), 0, stream>>>(x, out);
}

// Round 3
// 99.796 us; speedup vs baseline: 1.4230x; 1.4230x over previous
//
#include <hip/hip_runtime.h>

// EvoAttn: causal self-attention with Q=K=V = x.reshape(B,L,H,D).
// B=2 H=16 L=2048 D=128, fp32 in/out, bf16 MFMA compute.
// v3: pre-pass packs x into pre-swizzled bf16 tiles (kv + kvt layouts) in ws;
//     hot loop stages via global_load_lds (async, counted vmcnt pipeline).

#define TL 2048
#define TE 2048
#define TD 128
#define QB 64
#define KB 64
#define NT 32                      // TL / KB
#define TILE_B 16384               // 64*128*2 bytes per tile per layout
#define KV_REGION (2 * 16 * NT * TILE_B)   // 16 MB per layout
#define WS_NEED (2u * (unsigned)KV_REGION) // 32 MB

typedef __attribute__((ext_vector_type(8))) short bf16x8;
typedef __attribute__((ext_vector_type(4))) float f32x4;
typedef __attribute__((ext_vector_type(8))) unsigned short u16x8;
typedef __attribute__((ext_vector_type(4))) unsigned short u16x4;

// (1/sqrt(128)) * log2(e)
#define SCALE_LOG2E 0.12751879f

__device__ __forceinline__ unsigned short f2bf(float f) {
  unsigned int u = __builtin_bit_cast(unsigned int, f);
  u += 0x7fffu + ((u >> 16) & 1u);   // RNE
  return (unsigned short)(u >> 16);
}

__device__ __forceinline__ f32x4 mfma16(bf16x8 a, bf16x8 b, f32x4 c) {
  return __builtin_amdgcn_mfma_f32_16x16x32_bf16(a, b, c, 0, 0, 0);
}

__device__ __forceinline__ void gl_lds16(const void* g, void* l) {
  __builtin_amdgcn_global_load_lds(
      (__attribute__((address_space(1))) void*)(g),
      (__attribute__((address_space(3))) void*)(l), 16, 0, 0);
}

// kv: [64 rows k][128 d] bf16, row stride 256B, byte ^= (k&7)<<4
// kvt:[128 rows d][64 k] bf16, row stride 128B, byte ^= (d&7)<<4
__device__ __forceinline__ void stage_tile(const float* __restrict__ src,
                                           unsigned short* kv, unsigned short* kvt,
                                           int t) {
  const int kr = (t >> 4) << 2;   // 4 consecutive k-rows per thread
  const int d0 = (t & 15) << 3;   // 8 d-cols per thread
  unsigned short c[4][8];
#pragma unroll
  for (int rr = 0; rr < 4; ++rr) {
    const float* p = src + (kr + rr) * TE + d0;
    const float4 a = *(const float4*)p;
    const float4 b = *(const float4*)(p + 4);
    c[rr][0] = f2bf(a.x); c[rr][1] = f2bf(a.y); c[rr][2] = f2bf(a.z); c[rr][3] = f2bf(a.w);
    c[rr][4] = f2bf(b.x); c[rr][5] = f2bf(b.y); c[rr][6] = f2bf(b.z); c[rr][7] = f2bf(b.w);
  }
#pragma unroll
  for (int rr = 0; rr < 4; ++rr) {
    const int r = kr + rr;
    u16x8 o = {c[rr][0], c[rr][1], c[rr][2], c[rr][3],
               c[rr][4], c[rr][5], c[rr][6], c[rr][7]};
    const int off = (r * 256 + d0 * 2) ^ ((r & 7) << 4);
    *(u16x8*)((char*)kv + off) = o;
  }
#pragma unroll
  for (int cc = 0; cc < 8; ++cc) {
    const int d = d0 + cc;
    u16x4 o = {c[0][cc], c[1][cc], c[2][cc], c[3][cc]};
    const int off = (d * 128 + kr * 2) ^ ((d & 7) << 4);
    *(u16x4*)((char*)kvt + off) = o;
  }
}

__device__ __forceinline__ bf16x8 ld256(const unsigned short* base, int row, int inrow) {
  const int off = (row * 256 + inrow) ^ ((row & 7) << 4);
  return *(const bf16x8*)((const char*)base + off);
}
__device__ __forceinline__ bf16x8 ld128(const unsigned short* base, int row, int inrow) {
  const int off = (row * 128 + inrow) ^ ((row & 7) << 4);
  return *(const bf16x8*)((const char*)base + off);
}

// ---------------- pre-pass: x (f32) -> pre-swizzled bf16 tile images in ws --
__global__ void __launch_bounds__(256)
prepack(const float* __restrict__ x, char* __restrict__ wsb) {
  __shared__ unsigned short kv[QB * TD];
  __shared__ unsigned short kvt[TD * KB];
  const int bid = blockIdx.x;            // bh*32 + kt
  const int kt = bid & 31;
  const int bh = bid >> 5;
  const int b = bh >> 4;
  const int h = bh & 15;
  const float* src = x + (size_t)b * TL * TE + h * TD + (size_t)kt * KB * TE;
  stage_tile(src, kv, kvt, threadIdx.x);
  __syncthreads();
  char* gkv = wsb + (size_t)bid * TILE_B;
  char* gkt = wsb + KV_REGION + (size_t)bid * TILE_B;
  const char* lv = (const char*)kv;
  const char* lt = (const char*)kvt;
  const int t = threadIdx.x;
#pragma unroll
  for (int i = 0; i < 4; ++i) {   // 64B per thread per array, fully coalesced
    *(u16x8*)(gkv + t * 64 + i * 16) = *(const u16x8*)(lv + t * 64 + i * 16);
    *(u16x8*)(gkt + t * 64 + i * 16) = *(const u16x8*)(lt + t * 64 + i * 16);
  }
}

// ---------------- main attention kernel (async staged) ----------------------
__global__ void __launch_bounds__(256)
evo_attn2(const char* __restrict__ wsb, float* __restrict__ out) {
  // kv dbuf (2x16KB) + kvt single (16KB) + pl (8KB) = 56 KB
  __shared__ char smem[3 * TILE_B + 8192];

  const int t = threadIdx.x;
  const int lane = t & 63;
  const int w = t >> 6;        // wave 0..3, owns q rows [16w,16w+16)
  const int g = lane >> 4;     // lane group 0..3
  const int q15 = lane & 15;

  const int bh = blockIdx.x & 31;
  const int qt = 31 - (blockIdx.x >> 5);   // heavy (large qt) blocks first
  const int b = bh >> 4;
  const int h = bh & 15;
  const int q0 = qt * QB;

  const char* gkv = wsb + (size_t)bh * (NT * TILE_B);
  const char* gkt = wsb + KV_REGION + (size_t)bh * (NT * TILE_B);

  unsigned short* kvt = (unsigned short*)(smem + 2 * TILE_B);
  unsigned short* plw = (unsigned short*)(smem + 3 * TILE_B) + w * (16 * KB);

  // async stage: 16 chunks of 1KB per tile, wave w takes chunks [4w,4w+4)
#define STAGE_KV(BUFI, KT)                                                 \
  {                                                                        \
    char* dst_ = smem + (BUFI) * TILE_B;                                   \
    const char* src_ = gkv + (KT) * TILE_B;                                \
    _Pragma("unroll")                                                      \
    for (int i_ = 0; i_ < 4; ++i_) {                                       \
      const int c_ = (w * 4 + i_) * 1024;                                  \
      gl_lds16(src_ + c_ + lane * 16, dst_ + c_);                          \
    }                                                                      \
  }
#define STAGE_KT(KT)                                                       \
  {                                                                        \
    char* dst_ = smem + 2 * TILE_B;                                        \
    const char* src_ = gkt + (KT) * TILE_B;                                \
    _Pragma("unroll")                                                      \
    for (int i_ = 0; i_ < 4; ++i_) {                                       \
      const int c_ = (w * 4 + i_) * 1024;                                  \
      gl_lds16(src_ + c_ + lane * 16, dst_ + c_);                          \
    }                                                                      \
  }

  // prologue: diagonal tile (it is both the Q tile and KV tile 's=0')
  STAGE_KV(0, qt);
  STAGE_KT(qt);
  asm volatile("s_waitcnt vmcnt(0)" ::: "memory");
  __builtin_amdgcn_s_barrier();
  asm volatile("" ::: "memory");

  // Q fragments from kv buf0: lane holds Q[q0+16w+q15][c*32 + g*8 + j]
  bf16x8 qf[4];
#pragma unroll
  for (int c = 0; c < 4; ++c)
    qf[c] = ld256((const unsigned short*)smem, 16 * w + q15, c * 64 + g * 16);

  f32x4 acc[8];
#pragma unroll
  for (int dt = 0; dt < 8; ++dt) acc[dt] = (f32x4){0.f, 0.f, 0.f, 0.f};
  float mrun = -1e30f;
  float lrun = 0.f;

  // s = 0: diagonal tile (masked). s>0: tile index s-1.
  for (int s = 0; s <= qt; ++s) {
    // issue next kv tile loads into the other buffer (async)
    if (s < qt) STAGE_KV((s + 1) & 1, s);

    if (s > 0) {  // wait: this iteration's kv tile complete (oldest 4 loads)
      if (s < qt) asm volatile("s_waitcnt vmcnt(8)" ::: "memory");
      else        asm volatile("s_waitcnt vmcnt(4)" ::: "memory");
      __builtin_amdgcn_s_barrier();
      asm volatile("" ::: "memory");
    }
    const unsigned short* kv = (const unsigned short*)(smem + (s & 1) * TILE_B);

    // S^T = K * Q^T : lane (g,q15) holds S[k = kt*16+g*4+r][q = q15]
    float sv[16];
    __builtin_amdgcn_s_setprio(1);
#pragma unroll
    for (int kt2 = 0; kt2 < 4; ++kt2) {
      f32x4 st = (f32x4){0.f, 0.f, 0.f, 0.f};
#pragma unroll
      for (int c = 0; c < 4; ++c) {
        bf16x8 kf = ld256(kv, kt2 * 16 + q15, c * 64 + g * 16);
        st = mfma16(kf, qf[c], st);
      }
#pragma unroll
      for (int r = 0; r < 4; ++r) sv[kt2 * 4 + r] = st[r] * SCALE_LOG2E;
    }
    __builtin_amdgcn_s_setprio(0);

    if (s == 0) {  // causal mask within the diagonal 64x64 block
      const int qrel = 16 * w + q15;
#pragma unroll
      for (int kt2 = 0; kt2 < 4; ++kt2)
#pragma unroll
        for (int r = 0; r < 4; ++r)
          if (kt2 * 16 + g * 4 + r > qrel) sv[kt2 * 4 + r] = -1e30f;
    }

    // online softmax (exp2 domain); 16 in-lane values share one q-row
    float tmax = sv[0];
#pragma unroll
    for (int i = 1; i < 16; ++i) tmax = fmaxf(tmax, sv[i]);
    tmax = fmaxf(tmax, __shfl_xor(tmax, 16));
    tmax = fmaxf(tmax, __shfl_xor(tmax, 32));

    const float mnew = fmaxf(mrun, tmax);
    const float al = exp2f(mrun - mnew);   // g-uniform
    mrun = mnew;

    float psum = 0.f;
    unsigned short pb[16];
#pragma unroll
    for (int i = 0; i < 16; ++i) {
      const float p = exp2f(sv[i] - mnew);
      psum += p;
      pb[i] = f2bf(p);
    }
    lrun = lrun * al + psum;   // per-lane partial; reduced across g at end

    // P^T -> LDS as P[q][k] (bf16) for the PV A-fragments
#pragma unroll
    for (int kt2 = 0; kt2 < 4; ++kt2) {
      u16x4 o = {pb[kt2 * 4], pb[kt2 * 4 + 1], pb[kt2 * 4 + 2], pb[kt2 * 4 + 3]};
      const int off = (q15 * 128 + kt2 * 32 + g * 8) ^ ((q15 & 7) << 4);
      *(u16x4*)((char*)plw + off) = o;
    }
    asm volatile("s_waitcnt lgkmcnt(0)" ::: "memory");

    if (s > 0) {  // wait: this iteration's kvt tile complete
      if (s < qt) asm volatile("s_waitcnt vmcnt(4)" ::: "memory");
      else        asm volatile("s_waitcnt vmcnt(0)" ::: "memory");
      __builtin_amdgcn_s_barrier();
      asm volatile("" ::: "memory");
    }

    // O rescale: acc rows are q_local = g*4+r, alpha lives at lane q15==that
    float ar[4];
#pragma unroll
    for (int r = 0; r < 4; ++r) ar[r] = __shfl(al, g * 4 + r);
#pragma unroll
    for (int dt = 0; dt < 8; ++dt)
#pragma unroll
      for (int r = 0; r < 4; ++r) acc[dt][r] *= ar[r];

    // PV: acc[dt] += P(16xKB) * V(KBx16 slice dt)
    bf16x8 pa0 = ld128(plw, q15, g * 16);
    bf16x8 pa1 = ld128(plw, q15, 64 + g * 16);
    __builtin_amdgcn_s_setprio(1);
#pragma unroll
    for (int dt = 0; dt < 8; ++dt) {
      bf16x8 vb0 = ld128(kvt, dt * 16 + q15, g * 16);
      bf16x8 vb1 = ld128(kvt, dt * 16 + q15, 64 + g * 16);
      acc[dt] = mfma16(pa0, vb0, acc[dt]);
      acc[dt] = mfma16(pa1, vb1, acc[dt]);
    }
    __builtin_amdgcn_s_setprio(0);

    if (s < qt) {  // everyone done reading this tile; then refill kvt (async)
      __builtin_amdgcn_s_barrier();
      asm volatile("" ::: "memory");
      STAGE_KT(s);
    }
  }

  // Full row sum: combine the 4 g-groups' partial sums.
  lrun += __shfl_xor(lrun, 16);
  lrun += __shfl_xor(lrun, 32);

  const float inv = 1.f / lrun;
  float ir[4];
#pragma unroll
  for (int r = 0; r < 4; ++r) ir[r] = __shfl(inv, g * 4 + r);

  float* ob = out + ((size_t)b * TL + q0 + 16 * w) * TE + h * TD;
#pragma unroll
  for (int dt = 0; dt < 8; ++dt)
#pragma unroll
    for (int r = 0; r < 4; ++r)
      ob[(g * 4 + r) * TE + dt * 16 + q15] = acc[dt][r] * ir[r];
}

// ---------------- fallback (v1, self-contained staging) ---------------------
__global__ void __launch_bounds__(256)
evo_attn(const float* __restrict__ x, float* __restrict__ out) {
  __shared__ unsigned short kv[QB * TD];
  __shared__ unsigned short kvt[TD * KB];
  __shared__ unsigned short pl[4 * 16 * KB];

  const int t = threadIdx.x;
  const int lane = t & 63;
  const int w = t >> 6;
  const int g = lane >> 4;
  const int q15 = lane & 15;

  const int bh = blockIdx.x & 31;
  const int qt = 31 - (blockIdx.x >> 5);
  const int b = bh >> 4;
  const int h = bh & 15;
  const float* xb = x + (size_t)b * TL * TE + h * TD;
  const int q0 = qt * QB;

  stage_tile(xb + (size_t)q0 * TE, kv, kvt, t);
  __syncthreads();

  bf16x8 qf[4];
#pragma unroll
  for (int c = 0; c < 4; ++c)
    qf[c] = ld256(kv, 16 * w + q15, c * 64 + g * 16);

  f32x4 acc[8];
#pragma unroll
  for (int dt = 0; dt < 8; ++dt) acc[dt] = (f32x4){0.f, 0.f, 0.f, 0.f};
  float mrun = -1e30f;
  float lrun = 0.f;
  unsigned short* plw = pl + w * (16 * KB);

  for (int s = 0; s <= qt; ++s) {
    if (s > 0) {
      __syncthreads();
      stage_tile(xb + (size_t)(s - 1) * KB * TE, kv, kvt, t);
      __syncthreads();
    }
    float sv[16];
#pragma unroll
    for (int kt2 = 0; kt2 < 4; ++kt2) {
      f32x4 st = (f32x4){0.f, 0.f, 0.f, 0.f};
#pragma unroll
      for (int c = 0; c < 4; ++c) {
        bf16x8 kf = ld256(kv, kt2 * 16 + q15, c * 64 + g * 16);
        st = mfma16(kf, qf[c], st);
      }
#pragma unroll
      for (int r = 0; r < 4; ++r) sv[kt2 * 4 + r] = st[r] * SCALE_LOG2E;
    }
    if (s == 0) {
      const int qrel = 16 * w + q15;
#pragma unroll
      for (int kt2 = 0; kt2 < 4; ++kt2)
#pragma unroll
        for (int r = 0; r < 4; ++r)
          if (kt2 * 16 + g * 4 + r > qrel) sv[kt2 * 4 + r] = -1e30f;
    }
    float tmax = sv[0];
#pragma unroll
    for (int i = 1; i < 16; ++i) tmax = fmaxf(tmax, sv[i]);
    tmax = fmaxf(tmax, __shfl_xor(tmax, 16));
    tmax = fmaxf(tmax, __shfl_xor(tmax, 32));
    const float mnew = fmaxf(mrun, tmax);
    const float al = exp2f(mrun - mnew);
    mrun = mnew;
    float psum = 0.f;
    unsigned short pb[16];
#pragma unroll
    for (int i = 0; i < 16; ++i) {
      const float p = exp2f(sv[i] - mnew);
      psum += p;
      pb[i] = f2bf(p);
    }
    lrun = lrun * al + psum;
#pragma unroll
    for (int kt2 = 0; kt2 < 4; ++kt2) {
      u16x4 o = {pb[kt2 * 4], pb[kt2 * 4 + 1], pb[kt2 * 4 + 2], pb[kt2 * 4 + 3]};
      const int off = (q15 * 128 + kt2 * 32 + g * 8) ^ ((q15 & 7) << 4);
      *(u16x4*)((char*)plw + off) = o;
    }
    asm volatile("s_waitcnt lgkmcnt(0)" ::: "memory");
    float ar[4];
#pragma unroll
    for (int r = 0; r < 4; ++r) ar[r] = __shfl(al, g * 4 + r);
#pragma unroll
    for (int dt = 0; dt < 8; ++dt)
#pragma unroll
      for (int r = 0; r < 4; ++r) acc[dt][r] *= ar[r];
    bf16x8 pa0 = ld128(plw, q15, g * 16);
    bf16x8 pa1 = ld128(plw, q15, 64 + g * 16);
#pragma unroll
    for (int dt = 0; dt < 8; ++dt) {
      bf16x8 vb0 = ld128(kvt, dt * 16 + q15, g * 16);
      bf16x8 vb1 = ld128(kvt, dt * 16 + q15, 64 + g * 16);
      acc[dt] = mfma16(pa0, vb0, acc[dt]);
      acc[dt] = mfma16(pa1, vb1, acc[dt]);
    }
  }

  lrun += __shfl_xor(lrun, 16);
  lrun += __shfl_xor(lrun, 32);
  const float inv = 1.f / lrun;
  float ir[4];
#pragma unroll
  for (int r = 0; r < 4; ++r) ir[r] = __shfl(inv, g * 4 + r);
  float* ob = out + ((size_t)b * TL + q0 + 16 * w) * TE + h * TD;
#pragma unroll
  for (int dt = 0; dt < 8; ++dt)
#pragma unroll
    for (int r = 0; r < 4; ++r)
      ob[(g * 4 + r) * TE + dt * 16 + q15] = acc[dt][r] * ir[r];
}

extern "C" void kernel_launch(void* const* d_in, const int* in_sizes, int n_in,
                              void* d_out, int out_size, void* d_ws, size_t ws_size,
                              hipStream_t stream) {
  const float* x = (const float*)d_in[0];
  float* out = (float*)d_out;
  (void)in_sizes; (void)n_in; (void)out_size;
  if (ws_size >= (size_t)WS_NEED) {
    char* wsb = (char*)d_ws;
    prepack<<<dim3(1024), dim3(256), 0, stream>>>(x, wsb);
    evo_attn2<<<dim3(1024), dim3(256), 0, stream>>>(wsb, out);
  } else {
    evo_attn<<<dim3(1024), dim3(256), 0, stream>>>(x, out);
  }
}